// Round 12
// baseline (207.550 us; speedup 1.0000x reference)
//
#include <hip/hip_runtime.h>
#include <hip/hip_bf16.h>

typedef __bf16 bf16;
typedef __attribute__((ext_vector_type(8))) __bf16 bf16x8;
typedef __attribute__((ext_vector_type(4))) __bf16 bf16x4;
typedef __attribute__((ext_vector_type(2))) __bf16 bf16x2;
typedef __attribute__((ext_vector_type(4))) float f32x4;

#define C_NODES 63
#define F_DIM   250
#define NEG_SLOPE 0.2f
#define BS 8              // batches (b values) per persistent block

// LDS map (73472 B -> 2 blocks/CU):
//   [0,     32768)  AFR: A-fragments of X (swzA). Rewritten per batch; the
//                   NaN-guard zero slots are never re-dirtied (persist).
//   [32768, 64768)  HSB: Hs[f][s] bf16, f<250 (swz row-local)
//   [64768, 65024)  AS: a_s[64] f32
//   [65024, 65280)  AD: a_d[64] f32
//   [65280, 73472)  ALPHA: alpha[64][64] bf16 (swz)
#define AFR_B     0
#define HSB       32768
#define OFF_AS    64768
#define OFF_AD    65024
#define ALPHA_B   65280
#define LDS_BYTES 73472

__device__ __forceinline__ int swz(int a) { return a ^ ((a >> 3) & 0x70); }
__device__ __forceinline__ int swzA(int a) {
    return a ^ ((((a >> 8) & 3) ^ ((a >> 10) & 3)) << 4) ^ (((a >> 12) & 1) << 6);
}

// Raw barrier with LDS drain only: does NOT drain vmcnt, so prefetch global
// loads and epilogue stores stay in flight across phases (m201 pattern).
__device__ __forceinline__ void barrier_lds() {
    asm volatile("s_waitcnt lgkmcnt(0)" ::: "memory");
    __builtin_amdgcn_s_barrier();
    __builtin_amdgcn_sched_barrier(0);
}

// Pack W (250x250 f32) into bf16 MFMA-B fragment order, padded to 256x256.
// Columns 250/251 hold ws = W@att_src and wd = W@att_dst, so GEMM1 emits the
// per-node scores a_s, a_d directly. Rows k>=250 are zero (kills A-garbage).
extern "C" __global__ __launch_bounds__(256)
void gat_prep(const float* __restrict__ W, const float* __restrict__ att_src,
              const float* __restrict__ att_dst, bf16* __restrict__ Wp) {
    int i = blockIdx.x * 256 + threadIdx.x;   // 0..65535
    int tile = i >> 9;
    int ln   = (i >> 3) & 63;
    int j    = i & 7;
    int kt = tile >> 4, nt = tile & 15;
    int k = kt * 32 + (ln >> 4) * 8 + j;
    int n = nt * 16 + (ln & 15);
    float v = 0.f;
    if (k < F_DIM) {
        if (n < F_DIM) {
            v = W[k * F_DIM + n];
        } else if (n == F_DIM || n == F_DIM + 1) {
            const float* att = (n == F_DIM) ? att_src : att_dst;
            float s = 0.f;
            for (int o = 0; o < F_DIM; ++o) s = fmaf(W[k * F_DIM + o], att[o], s);
            v = s;
        }
    }
    Wp[i] = (bf16)v;
}

// 512 threads = 8 waves; wave w owns output cols [w*32, w*32+32).
// Persistent: each block processes BS consecutive b, software-pipelining the
// x-read (register prefetch) and letting stores overlap the next batch.
extern "C" __global__ __launch_bounds__(512, 4)
void gat_main(const float* __restrict__ x, const bf16* __restrict__ Wp,
              const float* __restrict__ bias, float* __restrict__ out)
{
    __shared__ __align__(16) unsigned char smem[LDS_BYTES];
    const int tid  = threadIdx.x;
    const int lane = tid & 63;
    const int w    = tid >> 6;        // wave id 0..7
    const int fl   = lane & 15;
    const int fh   = lane >> 4;
    const int b0   = blockIdx.x * BS;

    const bf16x8* wpv = (const bf16x8*)Wp;

    // NaN-guard (ONCE): zero the A-frag slots the scatter never writes.
    // These persist across batches (scatter rewrites the same slots).
    if (tid < 64) {
        int base = swzA((((tid >> 4) * 8 + 7) << 10) + (48 + (tid & 15)) * 16);
        *(unsigned int*)(smem + base + 4) = 0u;
        *(unsigned long long*)(smem + base + 8) = 0ull;
    } else if (tid < 96) {
        int idx = tid - 64;
        int base = swzA(((24 + (idx >> 2)) << 10) + ((((idx & 3) << 4) | 15) * 16));
        *(f32x4*)(smem + base) = (f32x4){0.f, 0.f, 0.f, 0.f};
    }

    // bias preload (2 regs, held)
    float bv0, bv1;
    { int f = w * 32 + fl;      bv0 = (f < F_DIM) ? bias[f] : 0.f;
      f += 16;                  bv1 = (f < F_DIM) ? bias[f] : 0.f; }

    // Prime: stage b0 directly (63 rows x 32 col-groups of 8 floats)
    {
        const float* xb = x + (size_t)b0 * (C_NODES * F_DIM);
#pragma unroll
        for (int it = 0; it < 4; ++it) {
            int idx = tid + it * 512;
            if (idx < 2016) {
                int r = idx >> 5, g = idx & 31;
                const float* src = xb + r * F_DIM + g * 8;
                int dl = (r & 15) | ((g & 3) << 4);
                int base = swzA((((r >> 4) * 8 + (g >> 2)) << 10) + dl * 16);
                if (g < 31) {
                    float2 v0 = *(const float2*)(src);
                    float2 v1 = *(const float2*)(src + 2);
                    float2 v2 = *(const float2*)(src + 4);
                    float2 v3 = *(const float2*)(src + 6);
                    bf16x8 pk8 = { (bf16)v0.x, (bf16)v0.y, (bf16)v1.x, (bf16)v1.y,
                                   (bf16)v2.x, (bf16)v2.y, (bf16)v3.x, (bf16)v3.y };
                    *(bf16x8*)(smem + base) = pk8;
                } else {
                    float2 v0 = *(const float2*)(src);
                    bf16x2 pk2 = { (bf16)v0.x, (bf16)v0.y };
                    *(bf16x2*)(smem + base) = pk2;
                }
            }
        }
    }

    // Issue prefetch for b0+1 (32 regs; fly under GEMM1)
    float2 pf[4][4];
    {
        const float* xb = x + (size_t)(b0 + 1) * (C_NODES * F_DIM);
#pragma unroll
        for (int it = 0; it < 4; ++it) {
            int idx = tid + it * 512;
            if (idx < 2016) {
                int r = idx >> 5, g = idx & 31;
                const float* src = xb + r * F_DIM + g * 8;
                pf[it][0] = *(const float2*)(src);
                if (g < 31) {
                    pf[it][1] = *(const float2*)(src + 2);
                    pf[it][2] = *(const float2*)(src + 4);
                    pf[it][3] = *(const float2*)(src + 6);
                }
            }
        }
    }
    barrier_lds();   // A-frags[b0] visible

#pragma unroll 1
    for (int i = 0; i < BS; ++i) {
        const int b = b0 + i;

        // ---- A: GEMM1  H'[64][256] = X @ Wp ; cols 250/251 = a_s/a_d ----
        f32x4 acc[4][2];
#pragma unroll
        for (int mt = 0; mt < 4; ++mt) {
            acc[mt][0] = (f32x4){0.f, 0.f, 0.f, 0.f};
            acc[mt][1] = (f32x4){0.f, 0.f, 0.f, 0.f};
        }
#pragma unroll 1
        for (int kt = 0; kt < 8; ++kt) {
            bf16x8 bw0 = wpv[(kt * 16 + w * 2)     * 64 + lane];
            bf16x8 bw1 = wpv[(kt * 16 + w * 2 + 1) * 64 + lane];
#pragma unroll
            for (int mt = 0; mt < 4; ++mt) {
                bf16x8 af = *(const bf16x8*)(smem + swzA(((mt * 8 + kt) << 10) + lane * 16));
                acc[mt][0] = __builtin_amdgcn_mfma_f32_16x16x32_bf16(af, bw0, acc[mt][0], 0, 0, 0);
                acc[mt][1] = __builtin_amdgcn_mfma_f32_16x16x32_bf16(af, bw1, acc[mt][1], 0, 0, 0);
            }
        }
        barrier_lds();   // bar1: AFR reads done (and prev GEMM2's Hs reads done)

        // ---- B: Hs+AS/AD write; pf -> A-frags[b+1]; issue pf[b+2] ----
#pragma unroll
        for (int mt = 0; mt < 4; ++mt) {
            int s0 = mt * 16 + fh * 4;
#pragma unroll
            for (int nti = 0; nti < 2; ++nti) {
                int f = w * 32 + nti * 16 + fl;
                if (f < F_DIM) {
                    f32x4 v = acc[mt][nti];
                    bf16x4 hv = { (bf16)v.x, (bf16)v.y, (bf16)v.z, (bf16)v.w };
                    *(bf16x4*)(smem + swz(HSB + f * 128 + s0 * 2)) = hv;
                }
            }
        }
        if (w == 7 && (fl == 10 || fl == 11)) {      // cols 250 / 251
            float* dst = (float*)(smem + (fl == 10 ? OFF_AS : OFF_AD));
#pragma unroll
            for (int mt = 0; mt < 4; ++mt) {
                f32x4 v = acc[mt][1];
#pragma unroll
                for (int q = 0; q < 4; ++q) dst[mt * 16 + fh * 4 + q] = v[q];
            }
        }
        if (i + 1 < BS) {
            // consume pf (b+1) -> A-frags
#pragma unroll
            for (int it = 0; it < 4; ++it) {
                int idx = tid + it * 512;
                if (idx < 2016) {
                    int r = idx >> 5, g = idx & 31;
                    int dl = (r & 15) | ((g & 3) << 4);
                    int base = swzA((((r >> 4) * 8 + (g >> 2)) << 10) + dl * 16);
                    if (g < 31) {
                        bf16x8 pk8 = { (bf16)pf[it][0].x, (bf16)pf[it][0].y,
                                       (bf16)pf[it][1].x, (bf16)pf[it][1].y,
                                       (bf16)pf[it][2].x, (bf16)pf[it][2].y,
                                       (bf16)pf[it][3].x, (bf16)pf[it][3].y };
                        *(bf16x8*)(smem + base) = pk8;
                    } else {
                        bf16x2 pk2 = { (bf16)pf[it][0].x, (bf16)pf[it][0].y };
                        *(bf16x2*)(smem + base) = pk2;
                    }
                }
            }
            if (i + 2 < BS) {   // issue pf for b+2 (flies through C, D, next A)
                const float* xb = x + (size_t)(b0 + i + 2) * (C_NODES * F_DIM);
#pragma unroll
                for (int it = 0; it < 4; ++it) {
                    int idx = tid + it * 512;
                    if (idx < 2016) {
                        int r = idx >> 5, g = idx & 31;
                        const float* src = xb + r * F_DIM + g * 8;
                        pf[it][0] = *(const float2*)(src);
                        if (g < 31) {
                            pf[it][1] = *(const float2*)(src + 2);
                            pf[it][2] = *(const float2*)(src + 4);
                            pf[it][3] = *(const float2*)(src + 6);
                        }
                    }
                }
            }
        }
        barrier_lds();   // bar2: Hs + AS/AD + A-frags[b+1] ready

        // ---- C: softmax (block-wide, once): thread=(d=tid>>3, c=tid&7) ----
        {
            const float* AS  = (const float*)(smem + OFF_AS);
            const float* ADp = (const float*)(smem + OFF_AD);
            int d = tid >> 3;
            int c = tid & 7;
            float ad_v = ADp[d];
            f32x4 a0 = *(const f32x4*)(AS + c * 8);
            f32x4 a1 = *(const f32x4*)(AS + c * 8 + 4);
            float p[8];
#pragma unroll
            for (int k = 0; k < 4; ++k) {
                float e;
                e = a0[k] + ad_v; p[k]     = (e > 0.f) ? e : NEG_SLOPE * e;
                e = a1[k] + ad_v; p[4 + k] = (e > 0.f) ? e : NEG_SLOPE * e;
            }
            if (c == 7) p[7] = -3.0e38f;   // s=63 excluded (63 sources)
            float md = p[0];
#pragma unroll
            for (int k = 1; k < 8; ++k) md = fmaxf(md, p[k]);
            md = fmaxf(md, __shfl_xor(md, 1));
            md = fmaxf(md, __shfl_xor(md, 2));
            md = fmaxf(md, __shfl_xor(md, 4));
            float sum = 0.f;
#pragma unroll
            for (int k = 0; k < 8; ++k) { p[k] = __expf(p[k] - md); sum += p[k]; }
            sum += __shfl_xor(sum, 1);
            sum += __shfl_xor(sum, 2);
            sum += __shfl_xor(sum, 4);
            float rz = 1.f / sum;
            bf16x8 pk;
#pragma unroll
            for (int k = 0; k < 8; ++k) pk[k] = (bf16)(p[k] * rz);
            *(bf16x8*)(smem + swz(ALPHA_B + d * 128 + c * 16)) = pk;
        }
        barrier_lds();   // bar3: alpha ready

        // ---- D: GEMM2 + stores (stores overlap next batch's GEMM1) ----
        f32x4 acc2[4][2];
#pragma unroll
        for (int mt = 0; mt < 4; ++mt) {
            acc2[mt][0] = (f32x4){0.f, 0.f, 0.f, 0.f};
            acc2[mt][1] = (f32x4){0.f, 0.f, 0.f, 0.f};
        }
#pragma unroll 1
        for (int ks = 0; ks < 2; ++ks) {
            int kk = ks * 32 + fh * 8;
            bf16x8 hbf0 = *(const bf16x8*)(smem + swz(HSB + (w * 32 + fl)      * 128 + kk * 2));
            bf16x8 hbf1 = *(const bf16x8*)(smem + swz(HSB + (w * 32 + fl + 16) * 128 + kk * 2));
#pragma unroll
            for (int mt = 0; mt < 4; ++mt) {
                bf16x8 aal = *(const bf16x8*)(smem + swz(ALPHA_B + (mt * 16 + fl) * 128 + kk * 2));
                acc2[mt][0] = __builtin_amdgcn_mfma_f32_16x16x32_bf16(aal, hbf0, acc2[mt][0], 0, 0, 0);
                acc2[mt][1] = __builtin_amdgcn_mfma_f32_16x16x32_bf16(aal, hbf1, acc2[mt][1], 0, 0, 0);
            }
        }
        float* ob = out + (size_t)b * (C_NODES * F_DIM);
#pragma unroll
        for (int mt = 0; mt < 4; ++mt) {
#pragma unroll
            for (int q = 0; q < 4; ++q) {
                int r = mt * 16 + fh * 4 + q;
                if (r < C_NODES) {
                    int f = w * 32 + fl;
                    ob[r * F_DIM + f] = acc2[mt][0][q] + bv0;
                    f += 16;
                    if (f < F_DIM) ob[r * F_DIM + f] = acc2[mt][1][q] + bv1;
                }
            }
        }
        // loop: next GEMM1 reads A-frags[b+1] (ready since bar2); stores fly.
    }
}

extern "C" void kernel_launch(void* const* d_in, const int* in_sizes, int n_in,
                              void* d_out, int out_size, void* d_ws, size_t ws_size,
                              hipStream_t stream) {
    const float* x       = (const float*)d_in[0];
    const float* W       = (const float*)d_in[1];
    const float* att_src = (const float*)d_in[2];
    const float* att_dst = (const float*)d_in[3];
    const float* bias    = (const float*)d_in[4];
    float* out = (float*)d_out;
    bf16* Wp = (bf16*)d_ws;   // 65536 bf16 = 128 KB packed W (+score cols)

    gat_prep<<<256, 256, 0, stream>>>(W, att_src, att_dst, Wp);
    gat_main<<<512, 512, 0, stream>>>(x, Wp, bias, out);
}

// Round 13
// 137.948 us; speedup vs baseline: 1.5046x; 1.5046x over previous
//
#include <hip/hip_runtime.h>
#include <hip/hip_bf16.h>

typedef __bf16 bf16;
typedef __attribute__((ext_vector_type(8))) __bf16 bf16x8;
typedef __attribute__((ext_vector_type(2))) __bf16 bf16x2;
typedef __attribute__((ext_vector_type(4))) float f32x4;
typedef __attribute__((ext_vector_type(4))) unsigned int uint4v;

#define C_NODES 63
#define F_DIM   250
#define NEG_SLOPE 0.2f
#define BS 8               // batches per persistent block; grid 512 = 1 wave

// LDS map (74240 B -> 2 blocks/CU):
//   [0, 65520)      SLAB: X as f32, 63 rows x 1040 B stride (260 f32).
//                   DMA fills bytes [0,992) per row; cols 248/249 reg-staged
//                   at [992,1000); cols 250-255 zeroed once at [1000,1024).
//   [65536, 65792)  AS: a_s[64] f32
//   [65792, 66048)  AD: a_d[64] f32
//   [66048, 74240)  ALPHA: alpha[64][64] bf16 (swz, 128 B rows)
#define ROWB      1040
#define SLAB      0
#define OFF_AS    65536
#define OFF_AD    65792
#define ALPHA_B   66048
#define LDS_BYTES 74240

__device__ __forceinline__ int swz(int a) { return a ^ ((a >> 3) & 0x70); }

typedef const __attribute__((address_space(1))) void* gas_t;
typedef __attribute__((address_space(3))) void* las_t;
__device__ __forceinline__ void dma16(const void* g, void* l) {
    __builtin_amdgcn_global_load_lds((gas_t)g, (las_t)l, 16, 0, 0);
}

// lgkm-only barrier: DMA (vmcnt) stays in flight across phases.
__device__ __forceinline__ void bar_lgkm() {
    asm volatile("s_waitcnt lgkmcnt(0)" ::: "memory");
    __builtin_amdgcn_s_barrier();
    __builtin_amdgcn_sched_barrier(0);
}

// Pack W (250x250 f32) into bf16 MFMA-B fragment order, padded to 256x256.
// Columns 250/251 hold ws = W@att_src and wd = W@att_dst, so GEMM1 emits the
// per-node scores a_s, a_d directly. Rows k>=250 are zero (kills A-garbage).
extern "C" __global__ __launch_bounds__(256)
void gat_prep(const float* __restrict__ W, const float* __restrict__ att_src,
              const float* __restrict__ att_dst, bf16* __restrict__ Wp) {
    int i = blockIdx.x * 256 + threadIdx.x;   // 0..65535
    int tile = i >> 9;
    int ln   = (i >> 3) & 63;
    int j    = i & 7;
    int kt = tile >> 4, nt = tile & 15;
    int k = kt * 32 + (ln >> 4) * 8 + j;
    int n = nt * 16 + (ln & 15);
    float v = 0.f;
    if (k < F_DIM) {
        if (n < F_DIM) {
            v = W[k * F_DIM + n];
        } else if (n == F_DIM || n == F_DIM + 1) {
            const float* att = (n == F_DIM) ? att_src : att_dst;
            float s = 0.f;
            for (int o = 0; o < F_DIM; ++o) s = fmaf(W[k * F_DIM + o], att[o], s);
            v = s;
        }
    }
    Wp[i] = (bf16)v;
}

// 512 threads = 8 waves; wave w owns output cols [w*32, w*32+32).
extern "C" __global__ __launch_bounds__(512, 4)
void gat_main(const float* __restrict__ x, const bf16* __restrict__ Wp,
              const float* __restrict__ bias, float* __restrict__ out)
{
    __shared__ __align__(16) unsigned char smem[LDS_BYTES];
    const int tid  = threadIdx.x;
    const int lane = tid & 63;
    const int w    = tid >> 6;        // wave id 0..7
    const int fl   = lane & 15;
    const int fh   = lane >> 4;
    const int b0   = blockIdx.x * BS;

    const bf16x8* wpv = (const bf16x8*)Wp;

    // bias (2 regs, held)
    float bv0, bv1;
    { int f = w * 32 + fl;      bv0 = (f < F_DIM) ? bias[f] : 0.f;
      f += 16;                  bv1 = (f < F_DIM) ? bias[f] : 0.f; }

    // zero cols 250-255 of every slab row (once; DMA/tail never re-dirty)
    if (tid < 63) {
        *(unsigned long long*)(smem + SLAB + tid * ROWB + 1000) = 0ull;
        *(f32x4*)(smem + SLAB + tid * ROWB + 1008) = (f32x4){0.f, 0.f, 0.f, 0.f};
    }

    // prime batch b0: DMA rows (wave w stages rows w*8..w*8+7) + reg tail
    {
        const float* xb = x + (size_t)b0 * (C_NODES * F_DIM);
        float2 tl = {0.f, 0.f};
        if (tid < 63) tl = *(const float2*)(xb + tid * F_DIM + 248);
#pragma unroll
        for (int rr = 0; rr < 8; ++rr) {
            int r = w * 8 + rr;
            if (r < 63 && lane < 62)
                dma16(xb + r * F_DIM + lane * 4, smem + SLAB + r * ROWB);
        }
        if (tid < 63) *(float2*)(smem + SLAB + tid * ROWB + 992) = tl;
    }
    asm volatile("s_waitcnt vmcnt(0)" ::: "memory");
    bar_lgkm();      // slab[b0] ready

#pragma unroll 1
    for (int i = 0; i < BS; ++i) {
        const int b = b0 + i;
        const float* xnext = x + (size_t)(b + 1) * (C_NODES * F_DIM);

        // tail cols 248/249 of b+1: load EARLY so its wait is vmcnt(N), not 0
        float2 tl = {0.f, 0.f};
        if (i + 1 < BS && tid < 63) tl = *(const float2*)(xnext + tid * F_DIM + 248);

        // ---- A: GEMM1  H'[64][256] = X @ Wp ; cols 250/251 = a_s/a_d ----
        f32x4 acc[4][2];
#pragma unroll
        for (int mt = 0; mt < 4; ++mt) {
            acc[mt][0] = (f32x4){0.f, 0.f, 0.f, 0.f};
            acc[mt][1] = (f32x4){0.f, 0.f, 0.f, 0.f};
        }
#pragma unroll 1
        for (int kt = 0; kt < 8; ++kt) {
            bf16x8 bw0 = wpv[(kt * 16 + w * 2)     * 64 + lane];
            bf16x8 bw1 = wpv[(kt * 16 + w * 2 + 1) * 64 + lane];
#pragma unroll
            for (int mt = 0; mt < 4; ++mt) {
                int row = mt * 16 + fl;
                bf16x8 af;
                if (row < C_NODES) {
                    const f32x4* p = (const f32x4*)(smem + SLAB + row * ROWB + kt * 128 + fh * 32);
                    f32x4 lo = p[0], hi = p[1];
                    af = (bf16x8){ (bf16)lo.x, (bf16)lo.y, (bf16)lo.z, (bf16)lo.w,
                                   (bf16)hi.x, (bf16)hi.y, (bf16)hi.z, (bf16)hi.w };
                } else {
                    af = (bf16x8){(bf16)0.f,(bf16)0.f,(bf16)0.f,(bf16)0.f,
                                  (bf16)0.f,(bf16)0.f,(bf16)0.f,(bf16)0.f};
                }
                acc[mt][0] = __builtin_amdgcn_mfma_f32_16x16x32_bf16(af, bw0, acc[mt][0], 0, 0, 0);
                acc[mt][1] = __builtin_amdgcn_mfma_f32_16x16x32_bf16(af, bw1, acc[mt][1], 0, 0, 0);
            }
        }
        bar_lgkm();   // bar1: slab reads done -> safe to DMA next batch

        // ---- B: issue DMA(b+1); ASAD write; in-reg H transpose; tail write --
        if (i + 1 < BS) {
#pragma unroll
            for (int rr = 0; rr < 8; ++rr) {
                int r = w * 8 + rr;
                if (r < 63 && lane < 62)
                    dma16(xnext + r * F_DIM + lane * 4, smem + SLAB + r * ROWB);
            }
        }
        if (w == 7 && (fl == 10 || fl == 11)) {      // cols 250 / 251
            float* dst = (float*)(smem + (fl == 10 ? OFF_AS : OFF_AD));
#pragma unroll
            for (int mt = 0; mt < 4; ++mt) {
                f32x4 v = acc[mt][1];
#pragma unroll
                for (int q = 0; q < 4; ++q) dst[mt * 16 + fh * 4 + q] = v[q];
            }
        }
        // pack H C-frags to bf16 pairs, then shuffle-transpose to B-frags
        unsigned int pk[4][2][2];
#pragma unroll
        for (int mt = 0; mt < 4; ++mt)
#pragma unroll
            for (int nti = 0; nti < 2; ++nti) {
                f32x4 v = acc[mt][nti];
                bf16x2 p0 = { (bf16)v.x, (bf16)v.y };
                bf16x2 p1 = { (bf16)v.z, (bf16)v.w };
                pk[mt][nti][0] = __builtin_bit_cast(unsigned int, p0);
                pk[mt][nti][1] = __builtin_bit_cast(unsigned int, p1);
            }
        const int LA = ((fh & 1) << 5) + fl;
        const int LB = LA + 16;
        const bool fhHi = (fh & 2) != 0;
        uint4v hb[2][2];
#pragma unroll
        for (int nti = 0; nti < 2; ++nti)
#pragma unroll
            for (int kt2 = 0; kt2 < 2; ++kt2) {
                unsigned int u[4];
#pragma unroll
                for (int h = 0; h < 2; ++h) {
                    unsigned int a0 = __shfl(pk[kt2 * 2][nti][h],     LA);
                    unsigned int a1 = __shfl(pk[kt2 * 2 + 1][nti][h], LA);
                    u[h] = fhHi ? a1 : a0;
                    unsigned int c0 = __shfl(pk[kt2 * 2][nti][h],     LB);
                    unsigned int c1 = __shfl(pk[kt2 * 2 + 1][nti][h], LB);
                    u[2 + h] = fhHi ? c1 : c0;
                }
                hb[nti][kt2] = (uint4v){u[0], u[1], u[2], u[3]};
            }
        if (i + 1 < BS && tid < 63)
            *(float2*)(smem + SLAB + tid * ROWB + 992) = tl;
        bar_lgkm();   // bar2: ASAD visible (DMA still flying)

        // ---- C: softmax (block-wide, once): thread=(d=tid>>3, c=tid&7) ----
        {
            const float* AS  = (const float*)(smem + OFF_AS);
            const float* ADp = (const float*)(smem + OFF_AD);
            int d = tid >> 3;
            int c = tid & 7;
            float ad_v = ADp[d];
            f32x4 a0 = *(const f32x4*)(AS + c * 8);
            f32x4 a1 = *(const f32x4*)(AS + c * 8 + 4);
            float p[8];
#pragma unroll
            for (int k = 0; k < 4; ++k) {
                float e;
                e = a0[k] + ad_v; p[k]     = (e > 0.f) ? e : NEG_SLOPE * e;
                e = a1[k] + ad_v; p[4 + k] = (e > 0.f) ? e : NEG_SLOPE * e;
            }
            if (c == 7) p[7] = -3.0e38f;   // s=63 excluded (63 sources)
            float md = p[0];
#pragma unroll
            for (int k = 1; k < 8; ++k) md = fmaxf(md, p[k]);
            md = fmaxf(md, __shfl_xor(md, 1));
            md = fmaxf(md, __shfl_xor(md, 2));
            md = fmaxf(md, __shfl_xor(md, 4));
            float sum = 0.f;
#pragma unroll
            for (int k = 0; k < 8; ++k) { p[k] = __expf(p[k] - md); sum += p[k]; }
            sum += __shfl_xor(sum, 1);
            sum += __shfl_xor(sum, 2);
            sum += __shfl_xor(sum, 4);
            float rz = 1.f / sum;
            bf16x8 pkv;
#pragma unroll
            for (int k = 0; k < 8; ++k) pkv[k] = (bf16)(p[k] * rz);
            *(bf16x8*)(smem + swz(ALPHA_B + d * 128 + c * 16)) = pkv;
        }
        bar_lgkm();   // bar3: alpha ready

        // ---- D: GEMM2 (alpha LDS x transposed-H regs) + stores ----
        f32x4 acc2[4][2];
#pragma unroll
        for (int mt = 0; mt < 4; ++mt) {
            acc2[mt][0] = (f32x4){0.f, 0.f, 0.f, 0.f};
            acc2[mt][1] = (f32x4){0.f, 0.f, 0.f, 0.f};
        }
#pragma unroll
        for (int ks = 0; ks < 2; ++ks) {
            int kk = ks * 32 + fh * 8;
            bf16x8 h0 = __builtin_bit_cast(bf16x8, hb[0][ks]);
            bf16x8 h1 = __builtin_bit_cast(bf16x8, hb[1][ks]);
#pragma unroll
            for (int mt = 0; mt < 4; ++mt) {
                bf16x8 aal = *(const bf16x8*)(smem + swz(ALPHA_B + (mt * 16 + fl) * 128 + kk * 2));
                acc2[mt][0] = __builtin_amdgcn_mfma_f32_16x16x32_bf16(aal, h0, acc2[mt][0], 0, 0, 0);
                acc2[mt][1] = __builtin_amdgcn_mfma_f32_16x16x32_bf16(aal, h1, acc2[mt][1], 0, 0, 0);
            }
        }
        float* ob = out + (size_t)b * (C_NODES * F_DIM);
#pragma unroll
        for (int mt = 0; mt < 4; ++mt) {
#pragma unroll
            for (int q = 0; q < 4; ++q) {
                int r = mt * 16 + fh * 4 + q;
                if (r < C_NODES) {
                    int f = w * 32 + fl;
                    ob[r * F_DIM + f] = acc2[mt][0][q] + bv0;
                    f += 16;
                    if (f < F_DIM) ob[r * F_DIM + f] = acc2[mt][1][q] + bv1;
                }
            }
        }
        if (i + 1 < BS) {
            // 8 DMA ops are OLDER than the 32 stores just issued: vmcnt(32)
            // == "all DMA landed, stores may keep flying".
            asm volatile("s_waitcnt vmcnt(32)" ::: "memory");
            bar_lgkm();   // slab[b+1] visible to all waves
        }
    }
}

extern "C" void kernel_launch(void* const* d_in, const int* in_sizes, int n_in,
                              void* d_out, int out_size, void* d_ws, size_t ws_size,
                              hipStream_t stream) {
    const float* x       = (const float*)d_in[0];
    const float* W       = (const float*)d_in[1];
    const float* att_src = (const float*)d_in[2];
    const float* att_dst = (const float*)d_in[3];
    const float* bias    = (const float*)d_in[4];
    float* out = (float*)d_out;
    bf16* Wp = (bf16*)d_ws;   // 65536 bf16 = 128 KB packed W (+score cols)

    gat_prep<<<256, 256, 0, stream>>>(W, att_src, att_dst, Wp);
    gat_main<<<512, 512, 0, stream>>>(x, Wp, bias, out);
}